// Round 10
// baseline (434.420 us; speedup 1.0000x reference)
//
#include <hip/hip_runtime.h>
#include <hip/hip_bf16.h>
#include <math.h>

#define H 1024
#define F 3584
#define F2 7168
#define NE 8
#define T 1024

typedef __attribute__((ext_vector_type(4))) float f32x4;
typedef __attribute__((ext_vector_type(8))) short bf16x8;
typedef __attribute__((ext_vector_type(4))) unsigned u32x4;

__device__ inline short f2bf(float f) {
  union { float f; unsigned u; } v; v.f = f;
  unsigned r = (v.u + 0x7FFFu + ((v.u >> 16) & 1u)) >> 16;
  return (short)r;
}

__device__ inline unsigned pkbf(float a, float b) {
  unsigned r;
  asm("v_cvt_pk_bf16_f32 %0, %1, %2" : "=v"(r) : "v"(a), "v"(b));
  return r;
}

#define MFMA16(af, bf, c) __builtin_amdgcn_mfma_f32_16x16x32_bf16((af), (bf), (c), 0, 0, 0)

// load 8 fp32 at stride st (k-major weights), convert to bf16x8 (R7-proven shape)
__device__ inline bf16x8 ldcvt(const float* p, int st) {
  float f0 = p[0],      f1 = p[st],     f2 = p[2 * st], f3 = p[3 * st];
  float f4 = p[4 * st], f5 = p[5 * st], f6 = p[6 * st], f7 = p[7 * st];
  union { u32x4 u; bf16x8 h; } cv;
  cv.u[0] = pkbf(f0, f1); cv.u[1] = pkbf(f2, f3);
  cv.u[2] = pkbf(f4, f5); cv.u[3] = pkbf(f6, f7);
  return cv.h;
}

// ---------------- x -> bf16 prepass ----------------
__global__ __launch_bounds__(256) void cvtx_k(
    const float* __restrict__ x, unsigned short* __restrict__ xb)
{
  int i = (blockIdx.x * 256 + threadIdx.x) * 8;
  f32x4 a = *(const f32x4*)(x + i);
  f32x4 b = *(const f32x4*)(x + i + 4);
  u32x4 o;
  o[0] = pkbf(a[0], a[1]); o[1] = pkbf(a[2], a[3]);
  o[2] = pkbf(b[0], b[1]); o[3] = pkbf(b[2], b[3]);
  *(u32x4*)(xb + i) = o;
}

// ---------------- router: fp64 logits, top-2 ----------------
__global__ __launch_bounds__(64) void router_k(
    const float* __restrict__ x, const float* __restrict__ gw,
    float* __restrict__ logits, int* __restrict__ cnt,
    int* __restrict__ tok_e, int* __restrict__ tok_r, float* __restrict__ tok_w)
{
  int t = blockIdx.x, l = threadIdx.x;
  const float* xr = x + (size_t)t * H;
  double acc[NE];
  #pragma unroll
  for (int e = 0; e < NE; ++e) acc[e] = 0.0;
  for (int j = 0; j < H / 64; ++j) {
    int h = j * 64 + l;
    float xv = xr[h];
    #pragma unroll
    for (int e = 0; e < NE; ++e) acc[e] += (double)xv * (double)gw[e * H + h];
  }
  #pragma unroll
  for (int off = 32; off >= 1; off >>= 1) {
    #pragma unroll
    for (int e = 0; e < NE; ++e) acc[e] += __shfl_down(acc[e], off, 64);
  }
  if (l == 0) {
    float lg[NE];
    #pragma unroll
    for (int e = 0; e < NE; ++e) { lg[e] = (float)acc[e]; logits[t * NE + e] = lg[e]; }
    int i0 = 0;
    for (int e = 1; e < NE; ++e) if (lg[e] > lg[i0]) i0 = e;
    int i1 = (i0 == 0) ? 1 : 0;
    for (int e = 0; e < NE; ++e) if (e != i0 && lg[e] > lg[i1]) i1 = e;
    float w0 = 1.f / (1.f + expf(lg[i1] - lg[i0]));
    float w1 = 1.f / (1.f + expf(lg[i0] - lg[i1]));
    int r0 = atomicAdd(&cnt[i0], 1);
    int r1 = atomicAdd(&cnt[i1], 1);
    tok_e[2 * t] = i0;     tok_r[2 * t] = r0;     tok_w[2 * t] = w0;
    tok_e[2 * t + 1] = i1; tok_r[2 * t + 1] = r1; tok_w[2 * t + 1] = w1;
  }
}

// ---------------- scan + gather list ----------------
__global__ __launch_bounds__(1024) void build_k(
    const int* __restrict__ cnt, int* __restrict__ base,
    const int* __restrict__ tok_e, const int* __restrict__ tok_r,
    const float* __restrict__ tok_w, int* __restrict__ gtok, float* __restrict__ gws)
{
  __shared__ int sb[NE];
  if (threadIdx.x == 0) {
    int s = 0;
    for (int e = 0; e < NE; ++e) { sb[e] = s; base[e] = s; s += cnt[e]; }
  }
  __syncthreads();
  int t = threadIdx.x;
  #pragma unroll
  for (int k = 0; k < 2; ++k) {
    int e = tok_e[2 * t + k];
    int slot = sb[e] + tok_r[2 * t + k];
    gtok[slot] = t;
    gws[slot] = tok_w[2 * t + k];
  }
}

// ---------------- ffn1: NO-LDS register GEMM. M=128, N=256 (128g+128u), BK=32 ----------------
// Per wave-phase: 32 coalesced B dword loads + 4 ldcvt, 8 direct bf16 A loads, 32 MFMA.
__global__ __launch_bounds__(256, 2) void ffn1_k(
    const unsigned short* __restrict__ xb, const float* __restrict__ wgu,
    const int* __restrict__ cnt, const int* __restrict__ base,
    const int* __restrict__ gtok, unsigned short* __restrict__ act)
{
  // 1792 blocks = 8 XCD * 224; e = xcd, mB fastest (weight-panel L2 dedup)
  int wg = (blockIdx.x & 7) * 224 + (blockIdx.x >> 3);
  int mB = wg & 7;
  int rest = wg >> 3;               // 0..223
  int e = rest / 28, p = rest % 28;
  int n = cnt[e];
  int m0 = mB * 128;
  if (m0 >= n) return;
  int sb = base[e];
  int tid = threadIdx.x;
  int wv = tid >> 6, lane = tid & 63, lr = lane & 15, lg = lane >> 4;

  // B per-lane base: col = p*128 + wv*32 + lr (gate frag0), k = lg*8
  const float* Bq = wgu + (size_t)e * H * F2 + (size_t)(lg * 8) * F2 + p * 128 + wv * 32 + lr;

  // A per-lane row pointers (token gather, clamped): 8 m-frags
  const unsigned short* ax[8];
  #pragma unroll
  for (int mf = 0; mf < 8; ++mf) {
    int sl = m0 + mf * 16 + lr; if (sl >= n) sl = n - 1;
    ax[mf] = xb + (size_t)gtok[sb + sl] * H + lg * 8;
  }

  f32x4 acc[8][4];
  #pragma unroll
  for (int mf = 0; mf < 8; ++mf)
    #pragma unroll
    for (int cf = 0; cf < 4; ++cf) acc[mf][cf] = (f32x4)0.f;

  for (int s = 0; s < 32; ++s) {
    const float* bp = Bq + (size_t)s * 32 * F2;
    bf16x8 b0 = ldcvt(bp, F2);
    bf16x8 b1 = ldcvt(bp + 16, F2);
    bf16x8 b2 = ldcvt(bp + F, F2);
    bf16x8 b3 = ldcvt(bp + F + 16, F2);
    #pragma unroll
    for (int mf = 0; mf < 8; ++mf) {
      bf16x8 af = *(const bf16x8*)(ax[mf] + s * 32);
      acc[mf][0] = MFMA16(af, b0, acc[mf][0]);
      acc[mf][1] = MFMA16(af, b1, acc[mf][1]);
      acc[mf][2] = MFMA16(af, b2, acc[mf][2]);
      acc[mf][3] = MFMA16(af, b3, acc[mf][3]);
    }
  }

  // epilogue: silu(gate)*up; gate cf 0..1, up cf 2..3
  #pragma unroll
  for (int mf = 0; mf < 8; ++mf) {
    #pragma unroll
    for (int g = 0; g < 2; ++g) {
      int fcol = p * 128 + wv * 32 + g * 16 + lr;
      #pragma unroll
      for (int r = 0; r < 4; ++r) {
        int sl = m0 + mf * 16 + lg * 4 + r;
        if (sl < n) {
          float gg = acc[mf][g][r], u = acc[mf][g + 2][r];
          act[(size_t)(sb + sl) * F + fcol] = (unsigned short)f2bf(gg / (1.f + expf(-gg)) * u);
        }
      }
    }
  }
}

// ---------------- ffn2: NO-LDS register GEMM. M=128, N=128, BK=32, K-split x4 ----------------
__global__ __launch_bounds__(256, 2) void ffn2_k(
    const unsigned short* __restrict__ act, const float* __restrict__ wd,
    const int* __restrict__ cnt, const int* __restrict__ base,
    const int* __restrict__ gtok, const float* __restrict__ gws,
    float* __restrict__ out)
{
  // 2048 blocks = 8 XCD * 256; e = xcd: 8 mB * 8 p * 4 kh, mB fastest
  int wg = (blockIdx.x & 7) * 256 + (blockIdx.x >> 3);
  int mB = wg & 7;
  int r2 = wg >> 3;                 // 0..255 (per-xcd: xcd*32 + q)
  int p = r2 & 7;
  int kh = (r2 >> 3) & 3;
  int e = r2 >> 5;
  int n = cnt[e];
  int m0 = mB * 128;
  if (m0 >= n) return;
  int sb = base[e];
  int tid = threadIdx.x;
  int wv = tid >> 6, lane = tid & 63, lr = lane & 15, lg = lane >> 4;
  const int kbase = kh * 896;

  const float* Bq = wd + (size_t)e * F * H + (size_t)(kbase + lg * 8) * H + p * 128 + wv * 32 + lr;

  const unsigned short* ax[8];
  #pragma unroll
  for (int mf = 0; mf < 8; ++mf) {
    int sl = m0 + mf * 16 + lr; if (sl >= n) sl = n - 1;
    ax[mf] = act + (size_t)(sb + sl) * F + kbase + lg * 8;
  }

  f32x4 acc[8][2];
  #pragma unroll
  for (int mf = 0; mf < 8; ++mf) { acc[mf][0] = (f32x4)0.f; acc[mf][1] = (f32x4)0.f; }

  for (int s = 0; s < 28; ++s) {
    const float* bp = Bq + (size_t)s * 32 * H;
    bf16x8 b0 = ldcvt(bp, H);
    bf16x8 b1 = ldcvt(bp + 16, H);
    #pragma unroll
    for (int mf = 0; mf < 8; ++mf) {
      bf16x8 af = *(const bf16x8*)(ax[mf] + s * 32);
      acc[mf][0] = MFMA16(af, b0, acc[mf][0]);
      acc[mf][1] = MFMA16(af, b1, acc[mf][1]);
    }
  }

  #pragma unroll
  for (int mf = 0; mf < 8; ++mf) {
    #pragma unroll
    for (int cf = 0; cf < 2; ++cf) {
      int col = p * 128 + wv * 32 + cf * 16 + lr;
      #pragma unroll
      for (int r = 0; r < 4; ++r) {
        int sl = m0 + mf * 16 + lg * 4 + r;
        if (sl < n) {
          int slot = sb + sl;
          atomicAdd(&out[(size_t)gtok[slot] * H + col], gws[slot] * acc[mf][cf][r]);
        }
      }
    }
  }
}

extern "C" void kernel_launch(void* const* d_in, const int* in_sizes, int n_in,
                              void* d_out, int out_size, void* d_ws, size_t ws_size,
                              hipStream_t stream)
{
  const float* x   = (const float*)d_in[0];
  const float* gw  = (const float*)d_in[1];
  const float* wgu = (const float*)d_in[2];
  const float* wdn = (const float*)d_in[3];
  float* out = (float*)d_out;
  float* logits = out + (size_t)T * H;

  char* w = (char*)d_ws;
  int*   cnt = (int*)(w);
  int*   bs  = (int*)(w + 32);
  int*   te  = (int*)(w + 64);
  int*   tr  = (int*)(w + 64 + 8192);
  float* tw  = (float*)(w + 64 + 16384);
  int*   gt  = (int*)(w + 64 + 24576);
  float* gwt = (float*)(w + 64 + 32768);
  unsigned short* act = (unsigned short*)(w + 65536);          // 2048 x 3584 bf16 = 14.68 MB
  unsigned short* xb  = (unsigned short*)(w + 14745600);       // 1024 x 1024 bf16 = 2 MB

  hipMemsetAsync(d_out, 0, (size_t)T * H * sizeof(float), stream);
  hipMemsetAsync(cnt, 0, NE * sizeof(int), stream);
  cvtx_k<<<512, 256, 0, stream>>>(x, xb);
  router_k<<<T, 64, 0, stream>>>(x, gw, logits, cnt, te, tr, tw);
  build_k<<<1, 1024, 0, stream>>>(cnt, bs, te, tr, tw, gt, gwt);
  ffn1_k<<<1792, 256, 0, stream>>>(xb, wgu, cnt, bs, gt, act);
  ffn2_k<<<2048, 256, 0, stream>>>(act, wdn, cnt, bs, gt, gwt, out);
}